// Round 4
// baseline (25.711 us; speedup 1.0000x reference)
//
#include <hip/hip_runtime.h>

#define H_ 224
#define W_ 224
#define NIMG 48
#define NBINS 33        // bins 0..31 real; bin 32 = beyond t_max (ignored)
#define NW 16           // waves per block
#define ROWS_PER 56     // H_/4 row-groups of 56 rows, 4 col-groups of 63 cols

// smallest k in [0,32] with k * fl(1/31) >= x  (== searchsorted(linspace(0,1,32), x, 'left'))
__device__ __forceinline__ int bin_of(float x) {
    const float C = 1.0f / 31.0f;
    int k = (int)__builtin_ceilf(x * 31.0f);
    k = min(k, 32);
    if ((float)(k - 1) * C >= x) --k;          // k==0: (-1)*C >= x>=0 is false, safe
    else if ((float)k * C < x) ++k;
    return k;
}

__global__ __launch_bounds__(1024) void ecc_fused(const float* __restrict__ x,
                                                  float* __restrict__ out) {
    __shared__ int hist[NW][NBINS];
    const int tid = threadIdx.x;
    const int wave = tid >> 6;
    const int lane = tid & 63;

    // each wave inits its own histogram: same-wave LDS ordering, no barrier needed
    if (lane < NBINS) hist[wave][lane] = 0;

    const int img  = blockIdx.x;
    const int rowg = wave >> 2;                 // 0..3
    const int colg = wave & 3;                  // 0..3
    const int col  = colg * 63 + lane;          // 1-col halo overlap between groups
    const bool produce = (lane < 63) && (col < W_);
    const bool hasR    = produce && (col < W_ - 1);
    const int  colc    = min(col, W_ - 1);      // clamp inactive lanes' loads
    const int  r0      = rowg * ROWS_PER;

    const float* base = x + (size_t)img * (H_ * W_) + (size_t)r0 * W_ + colc;
    int* hw = hist[wave];

    int bcur = bin_of(base[0]);

#pragma unroll 8
    for (int ri = 0; ri < ROWS_PER; ++ri) {
        const bool hasD = (r0 + ri < H_ - 1);   // wave-uniform
        int bnext = hasD ? bin_of(base[(ri + 1) * W_]) : 0;
        int sh = __shfl_down(bcur | (bnext << 16), 1, 64);
        int bR = sh & 0xffff, bDR = sh >> 16;
        if (hasD) {
            int e1 = max(bcur, bR);
            int e2 = max(bcur, bnext);
            if (hasR) {
                int lo = min(e1, e2), hi = max(e1, e2);
                int sq = max(hi, bDR);
                if (bcur != lo) { atomicAdd(&hw[bcur], 1); atomicAdd(&hw[lo], -1); }
                if (sq != hi)   { atomicAdd(&hw[sq], 1);   atomicAdd(&hw[hi], -1); }
            } else if (produce) {               // col 223: pixel + v-edge only
                if (bcur != e2) { atomicAdd(&hw[bcur], 1); atomicAdd(&hw[e2], -1); }
            }
        } else {                                // row 223: pixel + h-edge only
            int e1 = max(bcur, bR);
            if (hasR) {
                if (bcur != e1) { atomicAdd(&hw[bcur], 1); atomicAdd(&hw[e1], -1); }
            } else if (produce) {               // bottom-right corner
                atomicAdd(&hw[bcur], 1);
            }
        }
        bcur = bnext;
    }
    __syncthreads();

    // wave 0: sum the 16 per-wave histograms, inclusive scan, write output
    if (tid < 32) {
        int v = 0;
#pragma unroll
        for (int w = 0; w < NW; ++w) v += hist[w][tid];
        for (int off = 1; off < 32; off <<= 1) {
            int n = __shfl_up(v, off, 64);
            if (tid >= off) v += n;
        }
        out[img * 32 + tid] = (float)v;
    }
}

extern "C" void kernel_launch(void* const* d_in, const int* in_sizes, int n_in,
                              void* d_out, int out_size, void* d_ws, size_t ws_size,
                              hipStream_t stream) {
    const float* x = (const float*)d_in[0];
    float* out = (float*)d_out;
    ecc_fused<<<NIMG, 1024, 0, stream>>>(x, out);
}